// Round 8
// baseline (265.964 us; speedup 1.0000x reference)
//
#include <hip/hip_runtime.h>
#include <cstdint>

#define NPOS   32768   // B*H*W
#define KCODE  1024
#define DDIM   256

typedef unsigned long long u64;
typedef unsigned short u16;
typedef __attribute__((ext_vector_type(8))) short short8x;   // 8 bf16 (4 VGPR)
typedef __attribute__((ext_vector_type(4))) float f32x4;     // MFMA acc

__device__ __forceinline__ u16 bf16_rne(float x) {
  unsigned u = __float_as_uint(x);
  return (u16)((u + 0x7fffu + ((u >> 16) & 1u)) >> 16);
}
__device__ __forceinline__ float bf16_tof(u16 h) {
  return __uint_as_float(((unsigned)h) << 16);
}

// ---- kernel 0: pack W into MFMA-fragment-direct layout + wsq ---------------
// Virtual-K: chunks of 32 vd; c 0..7 -> Wh, 16..23 -> Wl (region 8..15 unused
// and not written).  frag = kh*768 + c*32 + cg*8 + ct; entry frag*64 + lane,
// lane = g*16 + m holds W[code = kh*512+cg*128+ct*16+m][vd = g*8+e].
__global__ void pack_w(const float* __restrict__ w, u16* __restrict__ Wp,
                       float* __restrict__ wsq) {
  const int t = threadIdx.x;              // 256 thr, 8 codes per block
  const int k = blockIdx.x * 8 + (t >> 5);
  const int sub = t & 31;                 // 32 threads per code
  const int g = sub & 3;
  const int dc = sub >> 2;                // d-chunk 0..7
  const int d0 = sub * 8;                 // = dc*32 + g*8
  float x[8];
  *(float4*)(x)     = *(const float4*)(w + (size_t)k * DDIM + d0);
  *(float4*)(x + 4) = *(const float4*)(w + (size_t)k * DDIM + d0 + 4);
  float s = 0.f;
  u16 h[8], lo[8];
  #pragma unroll
  for (int i = 0; i < 8; ++i) {
    s += x[i] * x[i];
    h[i] = bf16_rne(x[i]);
    lo[i] = bf16_rne(x[i] - bf16_tof(h[i]));
  }
  short8x hv, lv;
  #pragma unroll
  for (int i = 0; i < 8; ++i) { hv[i] = (short)h[i]; lv[i] = (short)lo[i]; }
  const int kh = k >> 9, cg = (k >> 7) & 3, ct = (k >> 4) & 7, m = k & 15;
  const int lane = g * 16 + m;
  const size_t off0 =
      ((size_t)(kh * 768 + dc * 32 + cg * 8 + ct) * 64 + lane) * 8;
  const size_t off2 =
      ((size_t)(kh * 768 + (16 + dc) * 32 + cg * 8 + ct) * 64 + lane) * 8;
  *(short8x*)(Wp + off0) = hv;
  *(short8x*)(Wp + off2) = lv;
  #pragma unroll
  for (int off = 16; off > 0; off >>= 1) s += __shfl_down(s, off, 32);
  if (sub == 0) wsq[k] = s;
}

// ---- kernel 1 (fused): UNCHANGED from R7 (baseline for the subtraction) ----
__global__ __launch_bounds__(512, 2) void argmin_fused(
    const float* __restrict__ z, const float* __restrict__ w,
    const u16* __restrict__ Wp, const float* __restrict__ wsq,
    float* __restrict__ out) {
  __shared__ __align__(16) char UB[64 * 257 * 4];
  __shared__ u64 Red[8][64];
  __shared__ int kvs[64];
  u16* Xs16 = (u16*)UB;
  float* G = (float*)UB;

  const int tid = threadIdx.x;
  const int l = tid & 63, wv = tid >> 6;
  const int g = l >> 4;

  const int bid = blockIdx.x;
  const int nb = (bid & 7) * 64 + (bid >> 3);
  const int n0 = nb * 64;
  const int bimg = n0 >> 10, hw0 = n0 & 1023;
  const float* zb = z + (size_t)bimg * (DDIM * 1024) + hw0;

  #pragma unroll
  for (int rr = 0; rr < 4; ++rr) {
    const int id = rr * 512 + tid;
    const int gg = id >> 6;
    const int nl = id & 63;
    float x[8];
    #pragma unroll
    for (int e = 0; e < 8; ++e)
      x[e] = zb[(size_t)(gg * 8 + e) * 1024 + nl];
    short8x hv, lv;
    #pragma unroll
    for (int e = 0; e < 8; ++e) {
      u16 hh = bf16_rne(x[e]);
      hv[e] = (short)hh;
      lv[e] = (short)bf16_rne(x[e] - bf16_tof(hh));
    }
    const int dc = gg >> 2, gq = gg & 3;
    const int nt = nl >> 4, mm = nl & 15;
    const int slot = (dc * 4 + nt) * 64 + gq * 16 + mm;
    *(short8x*)(&Xs16[(size_t)slot * 8]) = hv;
    *(short8x*)(&Xs16[(size_t)(slot + 2048) * 8]) = lv;
  }
  __syncthreads();

  const short8x* Xs = (const short8x*)Xs16;
  const short8x* Wf = (const short8x*)Wp +
      (size_t)((wv >> 2) * 768 + (wv & 3) * 8) * 64 + l;

  f32x4 acc[8][4];
  #pragma unroll
  for (int ct = 0; ct < 8; ++ct)
    #pragma unroll
    for (int nt = 0; nt < 4; ++nt) acc[ct][nt] = (f32x4){0.f, 0.f, 0.f, 0.f};

  short8x afA[8], afB[8], bfh[4], bfl[4];

  #pragma unroll
  for (int ct = 0; ct < 8; ++ct) afA[ct] = Wf[ct * 64];

  #pragma unroll 1
  for (int dc = 0; dc < 8; dc += 2) {
    {
      const int cn = dc + 1;
      #pragma unroll
      for (int ct = 0; ct < 8; ++ct) afB[ct] = Wf[(cn * 32 + ct) * 64];
      const short8x* Xh = Xs + dc * 256 + l;
      #pragma unroll
      for (int nt = 0; nt < 4; ++nt) bfh[nt] = Xh[nt * 64];
      const short8x* Xl = Xs + 2048 + dc * 256 + l;
      #pragma unroll
      for (int nt = 0; nt < 4; ++nt) bfl[nt] = Xl[nt * 64];
      #pragma unroll
      for (int nt = 0; nt < 4; ++nt)
        #pragma unroll
        for (int ct = 0; ct < 8; ++ct)
          acc[ct][nt] = __builtin_amdgcn_mfma_f32_16x16x32_bf16(
              afA[ct], bfh[nt], acc[ct][nt], 0, 0, 0);
      #pragma unroll
      for (int nt = 0; nt < 4; ++nt)
        #pragma unroll
        for (int ct = 0; ct < 8; ++ct)
          acc[ct][nt] = __builtin_amdgcn_mfma_f32_16x16x32_bf16(
              afA[ct], bfl[nt], acc[ct][nt], 0, 0, 0);
    }
    {
      const int dco = dc + 1;
      const int cn = (dc + 2 < 8) ? dc + 2 : 16;
      #pragma unroll
      for (int ct = 0; ct < 8; ++ct) afA[ct] = Wf[(cn * 32 + ct) * 64];
      const short8x* Xh = Xs + dco * 256 + l;
      #pragma unroll
      for (int nt = 0; nt < 4; ++nt) bfh[nt] = Xh[nt * 64];
      const short8x* Xl = Xs + 2048 + dco * 256 + l;
      #pragma unroll
      for (int nt = 0; nt < 4; ++nt) bfl[nt] = Xl[nt * 64];
      #pragma unroll
      for (int nt = 0; nt < 4; ++nt)
        #pragma unroll
        for (int ct = 0; ct < 8; ++ct)
          acc[ct][nt] = __builtin_amdgcn_mfma_f32_16x16x32_bf16(
              afB[ct], bfh[nt], acc[ct][nt], 0, 0, 0);
      #pragma unroll
      for (int nt = 0; nt < 4; ++nt)
        #pragma unroll
        for (int ct = 0; ct < 8; ++ct)
          acc[ct][nt] = __builtin_amdgcn_mfma_f32_16x16x32_bf16(
              afB[ct], bfl[nt], acc[ct][nt], 0, 0, 0);
    }
  }

  #pragma unroll 1
  for (int q = 0; q < 8; q += 2) {
    {
      const int cn = 16 + q + 1;
      #pragma unroll
      for (int ct = 0; ct < 8; ++ct) afB[ct] = Wf[(cn * 32 + ct) * 64];
      const short8x* Xh = Xs + q * 256 + l;
      #pragma unroll
      for (int nt = 0; nt < 4; ++nt) bfh[nt] = Xh[nt * 64];
      #pragma unroll
      for (int nt = 0; nt < 4; ++nt)
        #pragma unroll
        for (int ct = 0; ct < 8; ++ct)
          acc[ct][nt] = __builtin_amdgcn_mfma_f32_16x16x32_bf16(
              afA[ct], bfh[nt], acc[ct][nt], 0, 0, 0);
    }
    {
      const int cn = (q + 2 < 8) ? 16 + q + 2 : 16;
      #pragma unroll
      for (int ct = 0; ct < 8; ++ct) afA[ct] = Wf[(cn * 32 + ct) * 64];
      const short8x* Xh = Xs + (q + 1) * 256 + l;
      #pragma unroll
      for (int nt = 0; nt < 4; ++nt) bfh[nt] = Xh[nt * 64];
      #pragma unroll
      for (int nt = 0; nt < 4; ++nt)
        #pragma unroll
        for (int ct = 0; ct < 8; ++ct)
          acc[ct][nt] = __builtin_amdgcn_mfma_f32_16x16x32_bf16(
              afB[ct], bfh[nt], acc[ct][nt], 0, 0, 0);
    }
  }

  const int cbase = wv * 128;
  float4 wq[8];
  #pragma unroll
  for (int ct = 0; ct < 8; ++ct)
    wq[ct] = *(const float4*)(wsq + cbase + ct * 16 + g * 4);

  #pragma unroll
  for (int nt = 0; nt < 4; ++nt) {
    u64 best = ~0ull;
    #pragma unroll
    for (int ct = 0; ct < 8; ++ct) {
      const float* wqv = (const float*)&wq[ct];
      #pragma unroll
      for (int r = 0; r < 4; ++r) {
        float dist = wqv[r] - 2.0f * acc[ct][nt][r];
        unsigned u = __float_as_uint(dist);
        u = (u & 0x80000000u) ? ~u : (u | 0x80000000u);
        u64 key = ((u64)u << 32) | (unsigned)(cbase + ct * 16 + g * 4 + r);
        best = best < key ? best : key;
      }
    }
    u64 o = __shfl_xor(best, 16, 64); best = o < best ? o : best;
    o = __shfl_xor(best, 32, 64);     best = o < best ? o : best;
    if (l < 16) Red[wv][nt * 16 + l] = best;
  }
  __syncthreads();

  if (tid < 64) {
    u64 best = Red[0][tid];
    #pragma unroll
    for (int ww = 1; ww < 8; ++ww) {
      u64 o = Red[ww][tid];
      best = o < best ? o : best;
    }
    kvs[tid] = (int)(best & 0xffffffffull);
  }
  __syncthreads();

  #pragma unroll
  for (int i = 0; i < 8; ++i) {
    const int n = wv * 8 + i;
    const int k = kvs[n];
    float4 vv = *(const float4*)(w + (size_t)k * DDIM + l * 4);
    *(float4*)(&G[n * 257 + l * 4]) = vv;
  }
  __syncthreads();

  float* oc = out + (size_t)bimg * (DDIM * 1024) + hw0;
  #pragma unroll
  for (int cc = 0; cc < 32; ++cc) {
    const int c = cc * 8 + wv;
    float v = G[l * 257 + c];
    oc[(size_t)c * 1024 + l] = v;           // codes
    oc[(size_t)c * 1024 + l + 8388608] = v; // codes_bar
  }
}

// ---- DIAGNOSTIC (R8 only): R7 K-loop x4 reps, no prologue/epilogue ---------
// Same grid/threads/registers/W-stream as argmin_fused's main loop. LDS is
// read uninitialized (timing only). acc kept alive via asm (rule #17);
// per-rep pointer laundering defeats LICM so every rep re-issues all loads.
// L (one K-loop pass) = diag_dur / 8  (2 sequential blocks/CU x 4 reps).
__global__ __launch_bounds__(512, 2) void diag_kloop(const u16* __restrict__ Wp) {
  __shared__ __align__(16) char UB[64 * 257 * 4];
  const int tid = threadIdx.x;
  const int l = tid & 63, wv = tid >> 6;

  const short8x* Wf0 = (const short8x*)Wp +
      (size_t)((wv >> 2) * 768 + (wv & 3) * 8) * 64 + l;

  f32x4 acc[8][4];
  #pragma unroll
  for (int ct = 0; ct < 8; ++ct)
    #pragma unroll
    for (int nt = 0; nt < 4; ++nt) acc[ct][nt] = (f32x4){0.f, 0.f, 0.f, 0.f};

  #pragma unroll 1
  for (int rep = 0; rep < 4; ++rep) {
    const short8x* Xs = (const short8x*)UB;
    const short8x* Wf = Wf0;
    asm volatile("" : "+v"(Xs), "+v"(Wf));   // defeat LICM across reps

    short8x afA[8], afB[8], bfh[4], bfl[4];
    #pragma unroll
    for (int ct = 0; ct < 8; ++ct) afA[ct] = Wf[ct * 64];

    #pragma unroll 1
    for (int dc = 0; dc < 8; dc += 2) {
      {
        const int cn = dc + 1;
        #pragma unroll
        for (int ct = 0; ct < 8; ++ct) afB[ct] = Wf[(cn * 32 + ct) * 64];
        const short8x* Xh = Xs + dc * 256 + l;
        #pragma unroll
        for (int nt = 0; nt < 4; ++nt) bfh[nt] = Xh[nt * 64];
        const short8x* Xl = Xs + 2048 + dc * 256 + l;
        #pragma unroll
        for (int nt = 0; nt < 4; ++nt) bfl[nt] = Xl[nt * 64];
        #pragma unroll
        for (int nt = 0; nt < 4; ++nt)
          #pragma unroll
          for (int ct = 0; ct < 8; ++ct)
            acc[ct][nt] = __builtin_amdgcn_mfma_f32_16x16x32_bf16(
                afA[ct], bfh[nt], acc[ct][nt], 0, 0, 0);
        #pragma unroll
        for (int nt = 0; nt < 4; ++nt)
          #pragma unroll
          for (int ct = 0; ct < 8; ++ct)
            acc[ct][nt] = __builtin_amdgcn_mfma_f32_16x16x32_bf16(
                afA[ct], bfl[nt], acc[ct][nt], 0, 0, 0);
      }
      {
        const int dco = dc + 1;
        const int cn = (dc + 2 < 8) ? dc + 2 : 16;
        #pragma unroll
        for (int ct = 0; ct < 8; ++ct) afA[ct] = Wf[(cn * 32 + ct) * 64];
        const short8x* Xh = Xs + dco * 256 + l;
        #pragma unroll
        for (int nt = 0; nt < 4; ++nt) bfh[nt] = Xh[nt * 64];
        const short8x* Xl = Xs + 2048 + dco * 256 + l;
        #pragma unroll
        for (int nt = 0; nt < 4; ++nt) bfl[nt] = Xl[nt * 64];
        #pragma unroll
        for (int nt = 0; nt < 4; ++nt)
          #pragma unroll
          for (int ct = 0; ct < 8; ++ct)
            acc[ct][nt] = __builtin_amdgcn_mfma_f32_16x16x32_bf16(
                afB[ct], bfh[nt], acc[ct][nt], 0, 0, 0);
        #pragma unroll
        for (int nt = 0; nt < 4; ++nt)
          #pragma unroll
          for (int ct = 0; ct < 8; ++ct)
            acc[ct][nt] = __builtin_amdgcn_mfma_f32_16x16x32_bf16(
                afB[ct], bfl[nt], acc[ct][nt], 0, 0, 0);
      }
    }

    #pragma unroll 1
    for (int q = 0; q < 8; q += 2) {
      {
        const int cn = 16 + q + 1;
        #pragma unroll
        for (int ct = 0; ct < 8; ++ct) afB[ct] = Wf[(cn * 32 + ct) * 64];
        const short8x* Xh = Xs + q * 256 + l;
        #pragma unroll
        for (int nt = 0; nt < 4; ++nt) bfh[nt] = Xh[nt * 64];
        #pragma unroll
        for (int nt = 0; nt < 4; ++nt)
          #pragma unroll
          for (int ct = 0; ct < 8; ++ct)
            acc[ct][nt] = __builtin_amdgcn_mfma_f32_16x16x32_bf16(
                afA[ct], bfh[nt], acc[ct][nt], 0, 0, 0);
      }
      {
        const int cn = (q + 2 < 8) ? 16 + q + 2 : 16;
        #pragma unroll
        for (int ct = 0; ct < 8; ++ct) afA[ct] = Wf[(cn * 32 + ct) * 64];
        const short8x* Xh = Xs + (q + 1) * 256 + l;
        #pragma unroll
        for (int nt = 0; nt < 4; ++nt) bfh[nt] = Xh[nt * 64];
        #pragma unroll
        for (int nt = 0; nt < 4; ++nt)
          #pragma unroll
          for (int ct = 0; ct < 8; ++ct)
            acc[ct][nt] = __builtin_amdgcn_mfma_f32_16x16x32_bf16(
                afB[ct], bfh[nt], acc[ct][nt], 0, 0, 0);
      }
    }
  }

  #pragma unroll
  for (int ct = 0; ct < 8; ++ct)
    #pragma unroll
    for (int nt = 0; nt < 4; ++nt)
      asm volatile("" :: "v"(acc[ct][nt][0]), "v"(acc[ct][nt][1]),
                         "v"(acc[ct][nt][2]), "v"(acc[ct][nt][3]));
}

// ======================= fallback path (small workspace) ====================

__global__ void wt_kernel(const float* __restrict__ w, float* __restrict__ wt) {
  __shared__ float T[64][65];
  const int k0 = blockIdx.x * 64;
  const int d0 = blockIdx.y * 64;
  const int c = threadIdx.x & 63;
  const int r = threadIdx.x >> 6;
  #pragma unroll
  for (int p = 0; p < 16; ++p)
    T[p * 4 + r][c] = w[(size_t)(k0 + p * 4 + r) * DDIM + d0 + c];
  __syncthreads();
  #pragma unroll
  for (int p = 0; p < 16; ++p)
    wt[(size_t)(d0 + p * 4 + r) * KCODE + k0 + c] = T[c][p * 4 + r];
}

__global__ __launch_bounds__(512, 2) void argmin_mfma_v2(
    const float* __restrict__ z, const u16* __restrict__ Wp,
    const float* __restrict__ wsq, int* __restrict__ idx) {
  __shared__ __align__(16) u16 Xs[2 * 8 * 8 * 64 * 8];
  __shared__ u64 Red[8][128];

  const int tid = threadIdx.x;
  const int l = tid & 63, wv = tid >> 6;
  const int g = l >> 4;

  const int bid = blockIdx.x;
  const int nb = (bid & 7) * 32 + (bid >> 3);
  const int n0 = nb * 128;
  const int bimg = n0 >> 10, hw0 = n0 & 1023;
  const float* zb = z + (size_t)bimg * (DDIM * 1024) + hw0;

  #pragma unroll
  for (int rr = 0; rr < 8; ++rr) {
    const int id = rr * 512 + tid;
    const int gg = id >> 7;
    const int nl = id & 127;
    float x[8];
    #pragma unroll
    for (int e = 0; e < 8; ++e)
      x[e] = zb[(size_t)(gg * 8 + e) * 1024 + nl];
    short8x hv, lv;
    #pragma unroll
    for (int e = 0; e < 8; ++e) {
      u16 hh = bf16_rne(x[e]);
      hv[e] = (short)hh;
      lv[e] = (short)bf16_rne(x[e] - bf16_tof(hh));
    }
    const int dc = gg >> 2, gq = gg & 3;
    const int nt = nl >> 4, mm = nl & 15;
    const int slot = (dc * 8 + nt) * 64 + gq * 16 + mm;
    *(short8x*)(&Xs[(size_t)slot * 8]) = hv;
    *(short8x*)(&Xs[(size_t)(slot + 4096) * 8]) = lv;
  }
  __syncthreads();

  const short8x* WfBase =
      (const short8x*)Wp + (size_t)(((wv >> 1) & 3) * 8 + (wv & 1) * 4) * 64 + l;

  #pragma unroll 1
  for (int khp = 0; khp < 2; ++khp) {
    const short8x* Wf = WfBase + (size_t)khp * 49152;

    f32x4 acc[4][8];
    #pragma unroll
    for (int ct = 0; ct < 4; ++ct)
      #pragma unroll
      for (int nt = 0; nt < 8; ++nt) acc[ct][nt] = (f32x4){0.f, 0.f, 0.f, 0.f};

    #pragma unroll 1
    for (int dc = 0; dc < 8; ++dc) {
      short8x afh[4], afl[4];
      #pragma unroll
      for (int ct = 0; ct < 4; ++ct) afh[ct] = Wf[(dc * 32 + ct) * 64];
      const short8x* Xh = (const short8x*)Xs + dc * 512 + l;
      short8x bfh[8], bfl[8];
      #pragma unroll
      for (int nt = 0; nt < 8; ++nt) bfh[nt] = Xh[nt * 64];
      #pragma unroll
      for (int nt = 0; nt < 8; ++nt)
        #pragma unroll
        for (int ct = 0; ct < 4; ++ct)
          acc[ct][nt] = __builtin_amdgcn_mfma_f32_16x16x32_bf16(
              afh[ct], bfh[nt], acc[ct][nt], 0, 0, 0);
      #pragma unroll
      for (int ct = 0; ct < 4; ++ct) afl[ct] = Wf[((16 + dc) * 32 + ct) * 64];
      #pragma unroll
      for (int nt = 0; nt < 8; ++nt)
        #pragma unroll
        for (int ct = 0; ct < 4; ++ct)
          acc[ct][nt] = __builtin_amdgcn_mfma_f32_16x16x32_bf16(
              afl[ct], bfh[nt], acc[ct][nt], 0, 0, 0);
      const short8x* Xl = (const short8x*)Xs + 4096 + dc * 512 + l;
      #pragma unroll
      for (int nt = 0; nt < 8; ++nt) bfl[nt] = Xl[nt * 64];
      #pragma unroll
      for (int nt = 0; nt < 8; ++nt)
        #pragma unroll
        for (int ct = 0; ct < 4; ++ct)
          acc[ct][nt] = __builtin_amdgcn_mfma_f32_16x16x32_bf16(
              afh[ct], bfl[nt], acc[ct][nt], 0, 0, 0);
    }

    const int cbase = khp * 512 + wv * 64;
    float4 wq[4];
    #pragma unroll
    for (int ct = 0; ct < 4; ++ct)
      wq[ct] = *(const float4*)(wsq + cbase + ct * 16 + g * 4);

    #pragma unroll
    for (int nt = 0; nt < 8; ++nt) {
      u64 best = ~0ull;
      #pragma unroll
      for (int ct = 0; ct < 4; ++ct) {
        const float* wqv = (const float*)&wq[ct];
        #pragma unroll
        for (int r = 0; r < 4; ++r) {
          float dist = wqv[r] - 2.0f * acc[ct][nt][r];
          unsigned u = __float_as_uint(dist);
          u = (u & 0x80000000u) ? ~u : (u | 0x80000000u);
          u64 key = ((u64)u << 32) | (unsigned)(cbase + ct * 16 + g * 4 + r);
          best = best < key ? best : key;
        }
      }
      u64 o = __shfl_xor(best, 16, 64); best = o < best ? o : best;
      o = __shfl_xor(best, 32, 64);     best = o < best ? o : best;
      if (l < 16) {
        const int j = nt * 16 + l;
        if (khp == 0) Red[wv][j] = best;
        else { u64 p = Red[wv][j]; Red[wv][j] = best < p ? best : p; }
      }
    }
  }

  __syncthreads();
  if (tid < 128) {
    u64 best = Red[0][tid];
    #pragma unroll
    for (int ww = 1; ww < 8; ++ww) {
      u64 o = Red[ww][tid];
      best = o < best ? o : best;
    }
    idx[n0 + tid] = (int)(best & 0xffffffffull);
  }
}

#define WPITCH 1028
__global__ __launch_bounds__(256) void gather2_kernel(
    const float* __restrict__ wt, const int* __restrict__ idx,
    float* __restrict__ out) {
  __shared__ __align__(16) float Ws[16 * WPITCH];
  const int tid = threadIdx.x;
  const int bimg = blockIdx.x >> 4;
  const int c0 = (blockIdx.x & 15) * 16;
  int4 kv = *(const int4*)(idx + bimg * 1024 + tid * 4);
  #pragma unroll
  for (int cc = 0; cc < 16; ++cc) {
    float4 v = *(const float4*)(wt + (size_t)(c0 + cc) * KCODE + tid * 4);
    *(float4*)(Ws + cc * WPITCH + tid * 4) = v;
  }
  __syncthreads();
  float* ob = out + (size_t)bimg * DDIM * 1024 + (size_t)c0 * 1024 + tid * 4;
  #pragma unroll
  for (int cc = 0; cc < 16; ++cc) {
    const float* wr = Ws + cc * WPITCH;
    float4 v;
    v.x = wr[kv.x]; v.y = wr[kv.y]; v.z = wr[kv.z]; v.w = wr[kv.w];
    *(float4*)(ob + (size_t)cc * 1024) = v;
    *(float4*)(ob + (size_t)cc * 1024 + 8388608) = v;
  }
}

__global__ void gather_kernel(const float* __restrict__ w, const int* __restrict__ idx,
                              float* __restrict__ out) {
  const int gi = blockIdx.x * 256 + threadIdx.x;
  const int hw4 = gi & 255;
  const int c = (gi >> 8) & 255;
  const int b = gi >> 16;
  int4 kv = *(const int4*)(idx + b * 1024 + hw4 * 4);
  float4 v;
  v.x = w[(size_t)kv.x * 256 + c];
  v.y = w[(size_t)kv.y * 256 + c];
  v.z = w[(size_t)kv.z * 256 + c];
  v.w = w[(size_t)kv.w * 256 + c];
  float4* o = (float4*)out;
  o[gi] = v;
  o[gi + 2097152] = v;
}

extern "C" void kernel_launch(void* const* d_in, const int* in_sizes, int n_in,
                              void* d_out, int out_size, void* d_ws, size_t ws_size,
                              hipStream_t stream) {
  const float* z = (const float*)d_in[0];   // [32,256,32,32] fp32
  const float* w = (const float*)d_in[1];   // [1024,256] fp32
  float* out = (float*)d_out;

  float* wsq = (float*)d_ws;                 // 4 KB @ 0
  const size_t need_fused = 4096 + 1572864;  // wsq + Wp (1.5 MB)

  if (ws_size >= need_fused) {
    u16* Wp = (u16*)((char*)d_ws + 4096);
    pack_w<<<128, 256, 0, stream>>>(w, Wp, wsq);
    argmin_fused<<<512, 512, 0, stream>>>(z, w, Wp, wsq, out);
    // R8 DIAGNOSTIC: K-loop x4 in isolation (after the real kernel so it
    // cannot perturb argmin_fused's cache state). Removed next round.
    diag_kloop<<<512, 512, 0, stream>>>(Wp);
    return;
  }

  // -------- fallback: R2-style pipeline (Wp scratch inside codes_bar) -------
  int* idx = (int*)((char*)d_ws + 4096);
  const size_t need = 4096 + 131072 + 1048576;
  const bool ws_ok = ws_size >= need;
  float* wt = ws_ok ? (float*)((char*)d_ws + 4096 + 131072)
                    : out + (size_t)out_size - 262144;
  u16* Wp = (u16*)(out + 8388608);

  pack_w<<<128, 256, 0, stream>>>(w, Wp, wsq);
  wt_kernel<<<dim3(16, 4), 256, 0, stream>>>(w, wt);
  argmin_mfma_v2<<<256, 512, 0, stream>>>(z, Wp, wsq, idx);
  if (ws_ok)
    gather2_kernel<<<512, 256, 0, stream>>>(wt, idx, out);
  else
    gather_kernel<<<2097152 / 256, 256, 0, stream>>>(w, idx, out);
}

// Round 9
// 146.094 us; speedup vs baseline: 1.8205x; 1.8205x over previous
//
#include <hip/hip_runtime.h>
#include <cstdint>

#define NPOS   32768   // B*H*W
#define KCODE  1024
#define DDIM   256

typedef unsigned long long u64;
typedef unsigned short u16;
typedef __attribute__((ext_vector_type(8))) short short8x;    // 8 bf16 (4 VGPR)
typedef __attribute__((ext_vector_type(4))) float f32x4;      // 16x16 acc
typedef __attribute__((ext_vector_type(16))) float f32x16;    // 32x32 acc

__device__ __forceinline__ u16 bf16_rne(float x) {
  unsigned u = __float_as_uint(x);
  return (u16)((u + 0x7fffu + ((u >> 16) & 1u)) >> 16);
}
__device__ __forceinline__ float bf16_tof(u16 h) {
  return __uint_as_float(((unsigned)h) << 16);
}

// ---- kernel 0 (fused path): pack W for 32x32x16 MFMA frags + wsq -----------
// A-operand mapping (generalization of the end-to-end-verified 16x16 map):
//   lane = kg*32 + (code&31), elem e -> W[code][vd = dc*32 + ks*16 + kg*8 + e]
// Layout (short8x units): slot = ((cs*16 + wv)*4 + ct2*2 + ks)*64 + lane,
// cs = dc (hi) or 8+dc (lo); wv = code>>6, ct2 = (code>>5)&1.  Total 1 MB.
__global__ void pack_w32(const float* __restrict__ w, u16* __restrict__ Wp,
                         float* __restrict__ wsq) {
  const int t = threadIdx.x;              // 256 thr, 8 codes per block
  const int k = blockIdx.x * 8 + (t >> 5);
  const int sub = t & 31;                 // 32 threads per code, 8 d each
  const int d0 = sub * 8;
  float x[8];
  *(float4*)(x)     = *(const float4*)(w + (size_t)k * DDIM + d0);
  *(float4*)(x + 4) = *(const float4*)(w + (size_t)k * DDIM + d0 + 4);
  float s = 0.f;
  short8x hv, lv;
  #pragma unroll
  for (int i = 0; i < 8; ++i) {
    s += x[i] * x[i];
    u16 hh = bf16_rne(x[i]);
    hv[i] = (short)hh;
    lv[i] = (short)bf16_rne(x[i] - bf16_tof(hh));
  }
  const int wv = k >> 6, ct2 = (k >> 5) & 1, m31 = k & 31;
  const int dc = sub >> 2, ks = (sub >> 1) & 1, kg = sub & 1;
  const int lane = kg * 32 + m31;
  const size_t slotH = ((size_t)((dc * 16 + wv) * 4 + ct2 * 2 + ks)) * 64 + lane;
  const size_t slotL =
      ((size_t)(((8 + dc) * 16 + wv) * 4 + ct2 * 2 + ks)) * 64 + lane;
  *(short8x*)(Wp + slotH * 8) = hv;
  *(short8x*)(Wp + slotL * 8) = lv;
  #pragma unroll
  for (int off = 16; off > 0; off >>= 1) s += __shfl_down(s, off, 32);
  if (sub == 0) wsq[k] = s;
}

// ---- kernel 1 (fused): 32x32x16 MFMA dist-GEMM + argmin + gather + write ---
// R6 structure kept verbatim (best measured: 63.3 us): grid 512 XCD-swizzled,
// 1024 thr = 16 waves (4/SIMD), block = 1024 codes x 64 n, wave = 64 codes x
// 64 n, staggered dc start, no W prefetch.  R9 change: MFMA shape 16x16x32 ->
// 32x32x16 (2382 vs 2075 TF measured; MFMA instr count halves: 24/iter vs 48).
// acc = f32x16[2][2] = 64 regs (same budget as R6 -> 4 waves/SIMD preserved).
__global__ __launch_bounds__(1024) void argmin_fused(
    const float* __restrict__ z, const float* __restrict__ w,
    const u16* __restrict__ Wp, const float* __restrict__ wsq,
    float* __restrict__ out) {
  // union: X frags (64 KB) then padded gather buffer G[64][257] (65792 B)
  __shared__ __align__(16) char UB[64 * 257 * 4];
  __shared__ u64 Red[16][64];                       // 8 KB
  __shared__ int kvs[64];
  u16* Xs16 = (u16*)UB;
  float* G = (float*)UB;

  const int tid = threadIdx.x;
  const int l = tid & 63, wv = tid >> 6;            // wv 0..15

  // XCD swizzle: 512 wgs = 8 XCDs x 64 (bijective)
  const int bid = blockIdx.x;
  const int nb = (bid & 7) * 64 + (bid >> 3);
  const int n0 = nb * 64;
  const int bimg = n0 >> 10, hw0 = n0 & 1023;
  const float* zb = z + (size_t)bimg * (DDIM * 1024) + hw0;

  // ---- prologue: convert z slice (64 n x 256 d) -> B-operand frags ----
  // B mapping mirrors A: lane = kg*32 + (n&31), elem e -> X[n][dc*32+ks*16+kg*8+e]
  // slot (short8x) = (hl*32 + dc*4 + nt2*2 + ks)*64 + lane
  #pragma unroll
  for (int rr = 0; rr < 2; ++rr) {
    const int id = rr * 1024 + tid;
    const int gg = id >> 6;        // d-group 0..31 (8 d each)
    const int nl = id & 63;        // local n (lane-contiguous -> coalesced)
    float x[8];
    #pragma unroll
    for (int e = 0; e < 8; ++e)
      x[e] = zb[(size_t)(gg * 8 + e) * 1024 + nl];
    short8x hv, lv;
    #pragma unroll
    for (int e = 0; e < 8; ++e) {
      u16 hh = bf16_rne(x[e]);
      hv[e] = (short)hh;
      lv[e] = (short)bf16_rne(x[e] - bf16_tof(hh));
    }
    const int dc = gg >> 2, ks = (gg >> 1) & 1, kg = gg & 1;
    const int nt2 = nl >> 5, lane = kg * 32 + (nl & 31);
    const int slot = (dc * 4 + nt2 * 2 + ks) * 64 + lane;   // hl=0
    *(short8x*)(&Xs16[(size_t)slot * 8]) = hv;
    *(short8x*)(&Xs16[(size_t)(slot + 2048) * 8]) = lv;     // hl=1: +32*64
  }
  __syncthreads();   // Xs read-only from here until after the argmin barrier

  const short8x* Xb = (const short8x*)Xs16 + l;
  const short8x* Wb = (const short8x*)Wp + wv * 256 + l;    // wv*4*64

  f32x16 acc[2][2];
  #pragma unroll
  for (int a = 0; a < 2; ++a)
    #pragma unroll
    for (int b = 0; b < 2; ++b)
      #pragma unroll
      for (int r = 0; r < 16; ++r) acc[a][b][r] = 0.f;

  // anti-convoy stagger: SIMD-mates {wv, wv+4, wv+8, wv+12} -> 4 phases
  const int ph = (wv >> 2) * 2;

  #pragma unroll 1
  for (int it = 0; it < 8; ++it) {
    const int dc = (it + ph) & 7;
    short8x afh[4], afl[4], bfh[4], bfl[4];
    // W frags: f = ct2*2 + ks; hi at chunk-slot dc, lo at 8+dc (4096 = 64*64)
    #pragma unroll
    for (int f = 0; f < 4; ++f) afh[f] = Wb[(dc * 64 + f) * 64];
    #pragma unroll
    for (int f = 0; f < 4; ++f) afl[f] = Wb[((8 + dc) * 64 + f) * 64];
    // X hi frags: f = nt2*2 + ks
    #pragma unroll
    for (int f = 0; f < 4; ++f) bfh[f] = Xb[(dc * 4 + f) * 64];
    // region hh: Wh x Xh (k-accumulate over ks into the same acc tile)
    #pragma unroll
    for (int nt2 = 0; nt2 < 2; ++nt2)
      #pragma unroll
      for (int ct2 = 0; ct2 < 2; ++ct2)
        #pragma unroll
        for (int ks = 0; ks < 2; ++ks)
          acc[ct2][nt2] = __builtin_amdgcn_mfma_f32_32x32x16_bf16(
              afh[ct2 * 2 + ks], bfh[nt2 * 2 + ks], acc[ct2][nt2], 0, 0, 0);
    // X lo frags
    #pragma unroll
    for (int f = 0; f < 4; ++f) bfl[f] = Xb[(32 + dc * 4 + f) * 64];
    // region hl: Wh x Xl
    #pragma unroll
    for (int nt2 = 0; nt2 < 2; ++nt2)
      #pragma unroll
      for (int ct2 = 0; ct2 < 2; ++ct2)
        #pragma unroll
        for (int ks = 0; ks < 2; ++ks)
          acc[ct2][nt2] = __builtin_amdgcn_mfma_f32_32x32x16_bf16(
              afh[ct2 * 2 + ks], bfl[nt2 * 2 + ks], acc[ct2][nt2], 0, 0, 0);
    // region lh: Wl x Xh
    #pragma unroll
    for (int nt2 = 0; nt2 < 2; ++nt2)
      #pragma unroll
      for (int ct2 = 0; ct2 < 2; ++ct2)
        #pragma unroll
        for (int ks = 0; ks < 2; ++ks)
          acc[ct2][nt2] = __builtin_amdgcn_mfma_f32_32x32x16_bf16(
              afl[ct2 * 2 + ks], bfh[nt2 * 2 + ks], acc[ct2][nt2], 0, 0, 0);
  }

  // ---- epilogue: dist = wsq[k] - 2*dot, packed-key argmin ----
  // C/D 32x32 layout [m74/m101-verified]: col(n) = lane&31,
  // row(code) = (r&3) + 8*(r>>2) + 4*(lane>>5).
  const int cbase = wv * 64;
  const int hi = l >> 5;
  float4 wq[2][4];
  #pragma unroll
  for (int ct2 = 0; ct2 < 2; ++ct2)
    #pragma unroll
    for (int q = 0; q < 4; ++q)
      wq[ct2][q] = *(const float4*)(wsq + cbase + ct2 * 32 + q * 8 + hi * 4);

  #pragma unroll
  for (int nt2 = 0; nt2 < 2; ++nt2) {
    u64 best = ~0ull;
    #pragma unroll
    for (int ct2 = 0; ct2 < 2; ++ct2) {
      #pragma unroll
      for (int r = 0; r < 16; ++r) {
        const float* wqv = (const float*)&wq[ct2][r >> 2];
        float dist = wqv[r & 3] - 2.0f * acc[ct2][nt2][r];
        unsigned u = __float_as_uint(dist);
        u = (u & 0x80000000u) ? ~u : (u | 0x80000000u);  // monotone order
        const int code = cbase + ct2 * 32 + (r & 3) + 8 * (r >> 2) + 4 * hi;
        u64 key = ((u64)u << 32) | (unsigned)code;
        best = best < key ? best : key;                  // ties -> smallest k
      }
    }
    // lanes l and l^32 cover the same n (rows split by hi) -> merge
    u64 o = __shfl_xor(best, 32, 64);
    best = o < best ? o : best;
    if (l < 32) Red[wv][nt2 * 32 + l] = best;   // n_local = nt2*32 + (l&31)
  }
  __syncthreads();   // all waves done with Xs + Red complete

  if (tid < 64) {
    u64 best = Red[0][tid];
    #pragma unroll
    for (int ww = 1; ww < 16; ++ww) {
      u64 o = Red[ww][tid];
      best = o < best ? o : best;
    }
    kvs[tid] = (int)(best & 0xffffffffull);
  }
  __syncthreads();

  // ---- gather: stage winning w rows into G[n][c] (pitch 257, fp32) ----
  #pragma unroll
  for (int i = 0; i < 4; ++i) {
    const int n = wv * 4 + i;
    const int k = kvs[n];
    float4 vv = *(const float4*)(w + (size_t)k * DDIM + l * 4);
    *(float4*)(&G[n * 257 + l * 4]) = vv;   // lane l -> c = l*4..l*4+3
  }
  __syncthreads();

  // ---- write out: coalesced per-c rows; bank-rotated column reads ----
  float* oc = out + (size_t)bimg * (DDIM * 1024) + hw0;
  #pragma unroll
  for (int cc = 0; cc < 16; ++cc) {
    const int c = cc * 16 + wv;
    float v = G[l * 257 + c];               // bank = (l + c) & 31: conflict-free
    oc[(size_t)c * 1024 + l] = v;           // codes
    oc[(size_t)c * 1024 + l + 8388608] = v; // codes_bar
  }
}

// ======================= fallback path (small workspace) ====================
// Uses its own 16x16 pack layout (pack_w16) — independent of the fused path.

__global__ void pack_w16(const float* __restrict__ w, u16* __restrict__ Wp,
                         float* __restrict__ wsq) {
  const int t = threadIdx.x;
  const int k = blockIdx.x * 8 + (t >> 5);
  const int sub = t & 31;
  const int d0 = sub * 8;
  float x[8];
  *(float4*)(x)     = *(const float4*)(w + (size_t)k * DDIM + d0);
  *(float4*)(x + 4) = *(const float4*)(w + (size_t)k * DDIM + d0 + 4);
  float s = 0.f;
  short8x hv, lv;
  #pragma unroll
  for (int i = 0; i < 8; ++i) {
    s += x[i] * x[i];
    u16 hh = bf16_rne(x[i]);
    hv[i] = (short)hh;
    lv[i] = (short)bf16_rne(x[i] - bf16_tof(hh));
  }
  const int g = sub & 3, dc = sub >> 2;
  const int kh = k >> 9, cg = (k >> 7) & 3, ct = (k >> 4) & 7, m = k & 15;
  const int lane = g * 16 + m;
  const size_t off0 =
      ((size_t)(kh * 768 + dc * 32 + cg * 8 + ct) * 64 + lane) * 8;
  const size_t off2 =
      ((size_t)(kh * 768 + (16 + dc) * 32 + cg * 8 + ct) * 64 + lane) * 8;
  *(short8x*)(Wp + off0) = hv;
  *(short8x*)(Wp + off2) = lv;
  #pragma unroll
  for (int off = 16; off > 0; off >>= 1) s += __shfl_down(s, off, 32);
  if (sub == 0) wsq[k] = s;
}

__global__ void wt_kernel(const float* __restrict__ w, float* __restrict__ wt) {
  __shared__ float T[64][65];
  const int k0 = blockIdx.x * 64;
  const int d0 = blockIdx.y * 64;
  const int c = threadIdx.x & 63;
  const int r = threadIdx.x >> 6;
  #pragma unroll
  for (int p = 0; p < 16; ++p)
    T[p * 4 + r][c] = w[(size_t)(k0 + p * 4 + r) * DDIM + d0 + c];
  __syncthreads();
  #pragma unroll
  for (int p = 0; p < 16; ++p)
    wt[(size_t)(d0 + p * 4 + r) * KCODE + k0 + c] = T[c][p * 4 + r];
}

__global__ __launch_bounds__(512, 2) void argmin_mfma_v2(
    const float* __restrict__ z, const u16* __restrict__ Wp,
    const float* __restrict__ wsq, int* __restrict__ idx) {
  __shared__ __align__(16) u16 Xs[2 * 8 * 8 * 64 * 8];
  __shared__ u64 Red[8][128];

  const int tid = threadIdx.x;
  const int l = tid & 63, wv = tid >> 6;
  const int g = l >> 4;

  const int bid = blockIdx.x;
  const int nb = (bid & 7) * 32 + (bid >> 3);
  const int n0 = nb * 128;
  const int bimg = n0 >> 10, hw0 = n0 & 1023;
  const float* zb = z + (size_t)bimg * (DDIM * 1024) + hw0;

  #pragma unroll
  for (int rr = 0; rr < 8; ++rr) {
    const int id = rr * 512 + tid;
    const int gg = id >> 7;
    const int nl = id & 127;
    float x[8];
    #pragma unroll
    for (int e = 0; e < 8; ++e)
      x[e] = zb[(size_t)(gg * 8 + e) * 1024 + nl];
    short8x hv, lv;
    #pragma unroll
    for (int e = 0; e < 8; ++e) {
      u16 hh = bf16_rne(x[e]);
      hv[e] = (short)hh;
      lv[e] = (short)bf16_rne(x[e] - bf16_tof(hh));
    }
    const int dc = gg >> 2, gq = gg & 3;
    const int nt = nl >> 4, mm = nl & 15;
    const int slot = (dc * 8 + nt) * 64 + gq * 16 + mm;
    *(short8x*)(&Xs[(size_t)slot * 8]) = hv;
    *(short8x*)(&Xs[(size_t)(slot + 4096) * 8]) = lv;
  }
  __syncthreads();

  const short8x* WfBase =
      (const short8x*)Wp + (size_t)(((wv >> 1) & 3) * 8 + (wv & 1) * 4) * 64 + l;

  #pragma unroll 1
  for (int khp = 0; khp < 2; ++khp) {
    const short8x* Wf = WfBase + (size_t)khp * 49152;

    f32x4 acc[4][8];
    #pragma unroll
    for (int ct = 0; ct < 4; ++ct)
      #pragma unroll
      for (int nt = 0; nt < 8; ++nt) acc[ct][nt] = (f32x4){0.f, 0.f, 0.f, 0.f};

    #pragma unroll 1
    for (int dc = 0; dc < 8; ++dc) {
      short8x afh[4], afl[4];
      #pragma unroll
      for (int ct = 0; ct < 4; ++ct) afh[ct] = Wf[(dc * 32 + ct) * 64];
      const short8x* Xh = (const short8x*)Xs + dc * 512 + l;
      short8x bfh[8], bfl[8];
      #pragma unroll
      for (int nt = 0; nt < 8; ++nt) bfh[nt] = Xh[nt * 64];
      #pragma unroll
      for (int nt = 0; nt < 8; ++nt)
        #pragma unroll
        for (int ct = 0; ct < 4; ++ct)
          acc[ct][nt] = __builtin_amdgcn_mfma_f32_16x16x32_bf16(
              afh[ct], bfh[nt], acc[ct][nt], 0, 0, 0);
      #pragma unroll
      for (int ct = 0; ct < 4; ++ct) afl[ct] = Wf[((16 + dc) * 32 + ct) * 64];
      #pragma unroll
      for (int nt = 0; nt < 8; ++nt)
        #pragma unroll
        for (int ct = 0; ct < 4; ++ct)
          acc[ct][nt] = __builtin_amdgcn_mfma_f32_16x16x32_bf16(
              afl[ct], bfh[nt], acc[ct][nt], 0, 0, 0);
      const short8x* Xl = (const short8x*)Xs + 4096 + dc * 512 + l;
      #pragma unroll
      for (int nt = 0; nt < 8; ++nt) bfl[nt] = Xl[nt * 64];
      #pragma unroll
      for (int nt = 0; nt < 8; ++nt)
        #pragma unroll
        for (int ct = 0; ct < 4; ++ct)
          acc[ct][nt] = __builtin_amdgcn_mfma_f32_16x16x32_bf16(
              afh[ct], bfl[nt], acc[ct][nt], 0, 0, 0);
    }

    const int cbase = khp * 512 + wv * 64;
    float4 wq[4];
    #pragma unroll
    for (int ct = 0; ct < 4; ++ct)
      wq[ct] = *(const float4*)(wsq + cbase + ct * 16 + g * 4);

    #pragma unroll
    for (int nt = 0; nt < 8; ++nt) {
      u64 best = ~0ull;
      #pragma unroll
      for (int ct = 0; ct < 4; ++ct) {
        const float* wqv = (const float*)&wq[ct];
        #pragma unroll
        for (int r = 0; r < 4; ++r) {
          float dist = wqv[r] - 2.0f * acc[ct][nt][r];
          unsigned u = __float_as_uint(dist);
          u = (u & 0x80000000u) ? ~u : (u | 0x80000000u);
          u64 key = ((u64)u << 32) | (unsigned)(cbase + ct * 16 + g * 4 + r);
          best = best < key ? best : key;
        }
      }
      u64 o = __shfl_xor(best, 16, 64); best = o < best ? o : best;
      o = __shfl_xor(best, 32, 64);     best = o < best ? o : best;
      if (l < 16) {
        const int j = nt * 16 + l;
        if (khp == 0) Red[wv][j] = best;
        else { u64 p = Red[wv][j]; Red[wv][j] = best < p ? best : p; }
      }
    }
  }

  __syncthreads();
  if (tid < 128) {
    u64 best = Red[0][tid];
    #pragma unroll
    for (int ww = 1; ww < 8; ++ww) {
      u64 o = Red[ww][tid];
      best = o < best ? o : best;
    }
    idx[n0 + tid] = (int)(best & 0xffffffffull);
  }
}

#define WPITCH 1028
__global__ __launch_bounds__(256) void gather2_kernel(
    const float* __restrict__ wt, const int* __restrict__ idx,
    float* __restrict__ out) {
  __shared__ __align__(16) float Ws[16 * WPITCH];
  const int tid = threadIdx.x;
  const int bimg = blockIdx.x >> 4;
  const int c0 = (blockIdx.x & 15) * 16;
  int4 kv = *(const int4*)(idx + bimg * 1024 + tid * 4);
  #pragma unroll
  for (int cc = 0; cc < 16; ++cc) {
    float4 v = *(const float4*)(wt + (size_t)(c0 + cc) * KCODE + tid * 4);
    *(float4*)(Ws + cc * WPITCH + tid * 4) = v;
  }
  __syncthreads();
  float* ob = out + (size_t)bimg * DDIM * 1024 + (size_t)c0 * 1024 + tid * 4;
  #pragma unroll
  for (int cc = 0; cc < 16; ++cc) {
    const float* wr = Ws + cc * WPITCH;
    float4 v;
    v.x = wr[kv.x]; v.y = wr[kv.y]; v.z = wr[kv.z]; v.w = wr[kv.w];
    *(float4*)(ob + (size_t)cc * 1024) = v;
    *(float4*)(ob + (size_t)cc * 1024 + 8388608) = v;
  }
}

__global__ void gather_kernel(const float* __restrict__ w, const int* __restrict__ idx,
                              float* __restrict__ out) {
  const int gi = blockIdx.x * 256 + threadIdx.x;
  const int hw4 = gi & 255;
  const int c = (gi >> 8) & 255;
  const int b = gi >> 16;
  int4 kv = *(const int4*)(idx + b * 1024 + hw4 * 4);
  float4 v;
  v.x = w[(size_t)kv.x * 256 + c];
  v.y = w[(size_t)kv.y * 256 + c];
  v.z = w[(size_t)kv.z * 256 + c];
  v.w = w[(size_t)kv.w * 256 + c];
  float4* o = (float4*)out;
  o[gi] = v;
  o[gi + 2097152] = v;
}

extern "C" void kernel_launch(void* const* d_in, const int* in_sizes, int n_in,
                              void* d_out, int out_size, void* d_ws, size_t ws_size,
                              hipStream_t stream) {
  const float* z = (const float*)d_in[0];   // [32,256,32,32] fp32
  const float* w = (const float*)d_in[1];   // [1024,256] fp32
  float* out = (float*)d_out;

  float* wsq = (float*)d_ws;                 // 4 KB @ 0
  const size_t need_fused = 4096 + 1572864;  // wsq + Wp (<=1.5 MB)

  if (ws_size >= need_fused) {
    u16* Wp = (u16*)((char*)d_ws + 4096);
    pack_w32<<<128, 256, 0, stream>>>(w, Wp, wsq);
    argmin_fused<<<512, 1024, 0, stream>>>(z, w, Wp, wsq, out);
    return;
  }

  // -------- fallback: R2-style pipeline (Wp scratch inside codes_bar) -------
  int* idx = (int*)((char*)d_ws + 4096);
  const size_t need = 4096 + 131072 + 1048576;
  const bool ws_ok = ws_size >= need;
  float* wt = ws_ok ? (float*)((char*)d_ws + 4096 + 131072)
                    : out + (size_t)out_size - 262144;
  u16* Wp = (u16*)(out + 8388608);

  pack_w16<<<128, 256, 0, stream>>>(w, Wp, wsq);
  wt_kernel<<<dim3(16, 4), 256, 0, stream>>>(w, wt);
  argmin_mfma_v2<<<256, 512, 0, stream>>>(z, Wp, wsq, idx);
  if (ws_ok)
    gather2_kernel<<<512, 256, 0, stream>>>(wt, idx, out);
  else
    gather_kernel<<<2097152 / 256, 256, 0, stream>>>(w, idx, out);
}

// Round 10
// 142.319 us; speedup vs baseline: 1.8688x; 1.0265x over previous
//
#include <hip/hip_runtime.h>
#include <cstdint>

#define NPOS   32768   // B*H*W
#define KCODE  1024
#define DDIM   256

typedef unsigned long long u64;
typedef unsigned short u16;
typedef __attribute__((ext_vector_type(8))) short short8x;   // 8 bf16 (4 VGPR)
typedef __attribute__((ext_vector_type(4))) float f32x4;     // MFMA acc

__device__ __forceinline__ u16 bf16_rne(float x) {
  unsigned u = __float_as_uint(x);
  return (u16)((u + 0x7fffu + ((u >> 16) & 1u)) >> 16);
}
__device__ __forceinline__ float bf16_tof(u16 h) {
  return __uint_as_float(((unsigned)h) << 16);
}

// ---- kernel 0: pack W into MFMA-fragment-direct layout + wsq ---------------
// Virtual-K: chunks of 32 vd; c 0..7 -> Wh, 16..23 -> Wl (region 8..15 unused,
// not written).  frag = kh*768 + c*32 + cg*8 + ct; entry frag*64 + lane,
// lane = g*16 + m holds W[code = kh*512+cg*128+ct*16+m][vd = g*8+e].
__global__ void pack_w(const float* __restrict__ w, u16* __restrict__ Wp,
                       float* __restrict__ wsq) {
  const int t = threadIdx.x;              // 256 thr, 8 codes per block
  const int k = blockIdx.x * 8 + (t >> 5);
  const int sub = t & 31;                 // 32 threads per code
  const int g = sub & 3;
  const int dc = sub >> 2;                // d-chunk 0..7
  const int d0 = sub * 8;                 // = dc*32 + g*8
  float x[8];
  *(float4*)(x)     = *(const float4*)(w + (size_t)k * DDIM + d0);
  *(float4*)(x + 4) = *(const float4*)(w + (size_t)k * DDIM + d0 + 4);
  float s = 0.f;
  short8x hv, lv;
  #pragma unroll
  for (int i = 0; i < 8; ++i) {
    s += x[i] * x[i];
    u16 hh = bf16_rne(x[i]);
    hv[i] = (short)hh;
    lv[i] = (short)bf16_rne(x[i] - bf16_tof(hh));
  }
  const int kh = k >> 9, cg = (k >> 7) & 3, ct = (k >> 4) & 7, m = k & 15;
  const int lane = g * 16 + m;
  const size_t off0 =
      ((size_t)(kh * 768 + dc * 32 + cg * 8 + ct) * 64 + lane) * 8;
  const size_t off2 =
      ((size_t)(kh * 768 + (16 + dc) * 32 + cg * 8 + ct) * 64 + lane) * 8;
  *(short8x*)(Wp + off0) = hv;
  *(short8x*)(Wp + off2) = lv;
  #pragma unroll
  for (int off = 16; off > 0; off >>= 1) s += __shfl_down(s, off, 32);
  if (sub == 0) wsq[k] = s;
}

// ---- kernel 1 (fused): MFMA dist-GEMM + argmin + gather + out-write --------
// R6 structure VERBATIM (best measured: 63.3 us): grid 512 XCD-swizzled,
// 1024 thr = 16 waves (4/SIMD), block = 1024 codes x 64 n, wave = 64 codes x
// 64 n, acc[4][4], staggered dc start, no W prefetch, 16x16x32 MFMA.
// R10 change (cache policy only): z prologue loads and output stores are
// NON-TEMPORAL. Theory: the streaming output (8 MB/XCD/tranche through a
// 4 MB L2) evicts the shared 1 MB Wp reuse set, forcing the K-loop's W loads
// to L3 latency. nt keeps the stream from displacing Wp. Zero layout risk.
__global__ __launch_bounds__(1024) void argmin_fused(
    const float* __restrict__ z, const float* __restrict__ w,
    const u16* __restrict__ Wp, const float* __restrict__ wsq,
    float* __restrict__ out) {
  // union: X frags (64 KB) then padded gather buffer G[64][257] (65792 B)
  __shared__ __align__(16) char UB[64 * 257 * 4];
  __shared__ u64 Red[16][64];                       // 8 KB
  __shared__ int kvs[64];
  u16* Xs = (u16*)UB;
  float* G = (float*)UB;

  const int tid = threadIdx.x;
  const int l = tid & 63, wv = tid >> 6;
  const int g = l >> 4;

  // XCD swizzle: 512 wgs = 8 XCDs x 64 (bijective)
  const int bid = blockIdx.x;
  const int nb = (bid & 7) * 64 + (bid >> 3);
  const int n0 = nb * 64;
  const int bimg = n0 >> 10, hw0 = n0 & 1023;
  const float* zb = z + (size_t)bimg * (DDIM * 1024) + hw0;

  // ---- prologue: convert z slice (64 n x 256 d) -> bf16 hi/lo frags ----
  // slot (short8x) = hl*2048 + (dc*4 + nt)*64 + gq*16 + mm
  #pragma unroll
  for (int rr = 0; rr < 2; ++rr) {
    const int id = rr * 1024 + tid;
    const int gg = id >> 6;        // d-group 0..31 (8 d each)
    const int nl = id & 63;        // local n (lane-contiguous -> coalesced)
    float x[8];
    #pragma unroll
    for (int e = 0; e < 8; ++e)
      x[e] = __builtin_nontemporal_load(&zb[(size_t)(gg * 8 + e) * 1024 + nl]);
    short8x hv, lv;
    #pragma unroll
    for (int e = 0; e < 8; ++e) {
      u16 hh = bf16_rne(x[e]);
      hv[e] = (short)hh;
      lv[e] = (short)bf16_rne(x[e] - bf16_tof(hh));
    }
    const int dc = gg >> 2, gq = gg & 3;
    const int nt = nl >> 4, mm = nl & 15;
    const int slot = (dc * 4 + nt) * 64 + gq * 16 + mm;   // short8x units
    *(short8x*)(&Xs[(size_t)slot * 8]) = hv;
    *(short8x*)(&Xs[(size_t)(slot + 2048) * 8]) = lv;
  }
  __syncthreads();   // Xs read-only from here until after the argmin barrier

  // W frag base for wave wv (codes wv*64..+64 as 4 16-code tiles):
  // frag = (kh*24 + c)*32 + cgO*8 + ctO, kh=wv>>3, cgO=(wv>>1)&3, ctO=(wv&1)*4+ct
  const short8x* Wf = (const short8x*)Wp +
      (size_t)((wv >> 3) * 768 + ((wv >> 1) & 3) * 8 + (wv & 1) * 4) * 64 + l;

  f32x4 acc[4][4];
  #pragma unroll
  for (int ct = 0; ct < 4; ++ct)
    #pragma unroll
    for (int nt = 0; nt < 4; ++nt) acc[ct][nt] = (f32x4){0.f, 0.f, 0.f, 0.f};

  // anti-convoy stagger: SIMD-mates {wv, wv+4, wv+8, wv+12} -> 4 phases
  const int ph = (wv >> 2) * 2;

  #pragma unroll 1
  for (int it = 0; it < 8; ++it) {
    const int dc = (it + ph) & 7;
    short8x afh[4], afl[4], bfh[4], bfl[4];
    // issue both W streams up front: afl gets ~32 MFMA of cover before lh
    #pragma unroll
    for (int ct = 0; ct < 4; ++ct) afh[ct] = Wf[(dc * 32 + ct) * 64];
    #pragma unroll
    for (int ct = 0; ct < 4; ++ct) afl[ct] = Wf[((16 + dc) * 32 + ct) * 64];
    const short8x* Xh = (const short8x*)Xs + dc * 256 + l;
    #pragma unroll
    for (int nt = 0; nt < 4; ++nt) bfh[nt] = Xh[nt * 64];
    // region hh: Wh x Xh
    #pragma unroll
    for (int nt = 0; nt < 4; ++nt)
      #pragma unroll
      for (int ct = 0; ct < 4; ++ct)
        acc[ct][nt] = __builtin_amdgcn_mfma_f32_16x16x32_bf16(
            afh[ct], bfh[nt], acc[ct][nt], 0, 0, 0);
    const short8x* Xl = (const short8x*)Xs + 2048 + dc * 256 + l;
    #pragma unroll
    for (int nt = 0; nt < 4; ++nt) bfl[nt] = Xl[nt * 64];
    // region hl: Wh x Xl
    #pragma unroll
    for (int nt = 0; nt < 4; ++nt)
      #pragma unroll
      for (int ct = 0; ct < 4; ++ct)
        acc[ct][nt] = __builtin_amdgcn_mfma_f32_16x16x32_bf16(
            afh[ct], bfl[nt], acc[ct][nt], 0, 0, 0);
    // region lh: Wl x Xh (afl long since landed)
    #pragma unroll
    for (int nt = 0; nt < 4; ++nt)
      #pragma unroll
      for (int ct = 0; ct < 4; ++ct)
        acc[ct][nt] = __builtin_amdgcn_mfma_f32_16x16x32_bf16(
            afl[ct], bfh[nt], acc[ct][nt], 0, 0, 0);
  }

  // ---- epilogue: dist = wsq[k] - 2*dot, packed-key argmin ----
  const int cbase = wv * 64;
  float4 wq[4];
  #pragma unroll
  for (int ct = 0; ct < 4; ++ct)
    wq[ct] = *(const float4*)(wsq + cbase + ct * 16 + g * 4);

  #pragma unroll
  for (int nt = 0; nt < 4; ++nt) {
    u64 best = ~0ull;
    #pragma unroll
    for (int ct = 0; ct < 4; ++ct) {
      const float* wqv = (const float*)&wq[ct];
      #pragma unroll
      for (int r = 0; r < 4; ++r) {
        // C/D layout: row(code) = g*4 + r, col(n) = m   [m89-verified]
        float dist = wqv[r] - 2.0f * acc[ct][nt][r];
        unsigned u = __float_as_uint(dist);
        u = (u & 0x80000000u) ? ~u : (u | 0x80000000u);  // monotone order
        u64 key = ((u64)u << 32) | (unsigned)(cbase + ct * 16 + g * 4 + r);
        best = best < key ? best : key;                  // ties -> smallest k
      }
    }
    u64 o = __shfl_xor(best, 16, 64); best = o < best ? o : best;
    o = __shfl_xor(best, 32, 64);     best = o < best ? o : best;
    if (l < 16) Red[wv][nt * 16 + l] = best;   // j = nt*16 + m
  }
  __syncthreads();   // all waves done with Xs + Red complete

  if (tid < 64) {
    u64 best = Red[0][tid];
    #pragma unroll
    for (int ww = 1; ww < 16; ++ww) {
      u64 o = Red[ww][tid];
      best = o < best ? o : best;
    }
    kvs[tid] = (int)(best & 0xffffffffull);
  }
  __syncthreads();

  // ---- gather: stage winning w rows into G[n][c] (pitch 257, fp32) ----
  #pragma unroll
  for (int i = 0; i < 4; ++i) {
    const int n = wv * 4 + i;
    const int k = kvs[n];
    float4 vv = *(const float4*)(w + (size_t)k * DDIM + l * 4);
    *(float4*)(&G[n * 257 + l * 4]) = vv;   // lane l -> c = l*4..l*4+3
  }
  __syncthreads();

  // ---- write out: coalesced per-c rows, NON-TEMPORAL (don't evict Wp) ----
  float* oc = out + (size_t)bimg * (DDIM * 1024) + hw0;
  #pragma unroll
  for (int cc = 0; cc < 16; ++cc) {
    const int c = cc * 16 + wv;
    float v = G[l * 257 + c];               // bank = (l + c) & 31: conflict-free
    __builtin_nontemporal_store(v, &oc[(size_t)c * 1024 + l]);            // codes
    __builtin_nontemporal_store(v, &oc[(size_t)c * 1024 + l + 8388608]);  // codes_bar
  }
}

// ======================= fallback path (small workspace) ====================

__global__ void wt_kernel(const float* __restrict__ w, float* __restrict__ wt) {
  __shared__ float T[64][65];
  const int k0 = blockIdx.x * 64;
  const int d0 = blockIdx.y * 64;
  const int c = threadIdx.x & 63;
  const int r = threadIdx.x >> 6;
  #pragma unroll
  for (int p = 0; p < 16; ++p)
    T[p * 4 + r][c] = w[(size_t)(k0 + p * 4 + r) * DDIM + d0 + c];
  __syncthreads();
  #pragma unroll
  for (int p = 0; p < 16; ++p)
    wt[(size_t)(d0 + p * 4 + r) * KCODE + k0 + c] = T[c][p * 4 + r];
}

__global__ __launch_bounds__(512, 2) void argmin_mfma_v2(
    const float* __restrict__ z, const u16* __restrict__ Wp,
    const float* __restrict__ wsq, int* __restrict__ idx) {
  __shared__ __align__(16) u16 Xs[2 * 8 * 8 * 64 * 8];
  __shared__ u64 Red[8][128];

  const int tid = threadIdx.x;
  const int l = tid & 63, wv = tid >> 6;
  const int g = l >> 4;

  const int bid = blockIdx.x;
  const int nb = (bid & 7) * 32 + (bid >> 3);
  const int n0 = nb * 128;
  const int bimg = n0 >> 10, hw0 = n0 & 1023;
  const float* zb = z + (size_t)bimg * (DDIM * 1024) + hw0;

  #pragma unroll
  for (int rr = 0; rr < 8; ++rr) {
    const int id = rr * 512 + tid;
    const int gg = id >> 7;
    const int nl = id & 127;
    float x[8];
    #pragma unroll
    for (int e = 0; e < 8; ++e)
      x[e] = zb[(size_t)(gg * 8 + e) * 1024 + nl];
    short8x hv, lv;
    #pragma unroll
    for (int e = 0; e < 8; ++e) {
      u16 hh = bf16_rne(x[e]);
      hv[e] = (short)hh;
      lv[e] = (short)bf16_rne(x[e] - bf16_tof(hh));
    }
    const int dc = gg >> 2, gq = gg & 3;
    const int nt = nl >> 4, mm = nl & 15;
    const int slot = (dc * 8 + nt) * 64 + gq * 16 + mm;
    *(short8x*)(&Xs[(size_t)slot * 8]) = hv;
    *(short8x*)(&Xs[(size_t)(slot + 4096) * 8]) = lv;
  }
  __syncthreads();

  const short8x* WfBase =
      (const short8x*)Wp + (size_t)(((wv >> 1) & 3) * 8 + (wv & 1) * 4) * 64 + l;

  #pragma unroll 1
  for (int khp = 0; khp < 2; ++khp) {
    const short8x* Wf = WfBase + (size_t)khp * 49152;

    f32x4 acc[4][8];
    #pragma unroll
    for (int ct = 0; ct < 4; ++ct)
      #pragma unroll
      for (int nt = 0; nt < 8; ++nt) acc[ct][nt] = (f32x4){0.f, 0.f, 0.f, 0.f};

    #pragma unroll 1
    for (int dc = 0; dc < 8; ++dc) {
      short8x afh[4], afl[4];
      #pragma unroll
      for (int ct = 0; ct < 4; ++ct) afh[ct] = Wf[(dc * 32 + ct) * 64];
      const short8x* Xh = (const short8x*)Xs + dc * 512 + l;
      short8x bfh[8], bfl[8];
      #pragma unroll
      for (int nt = 0; nt < 8; ++nt) bfh[nt] = Xh[nt * 64];
      #pragma unroll
      for (int nt = 0; nt < 8; ++nt)
        #pragma unroll
        for (int ct = 0; ct < 4; ++ct)
          acc[ct][nt] = __builtin_amdgcn_mfma_f32_16x16x32_bf16(
              afh[ct], bfh[nt], acc[ct][nt], 0, 0, 0);
      #pragma unroll
      for (int ct = 0; ct < 4; ++ct) afl[ct] = Wf[((16 + dc) * 32 + ct) * 64];
      #pragma unroll
      for (int nt = 0; nt < 8; ++nt)
        #pragma unroll
        for (int ct = 0; ct < 4; ++ct)
          acc[ct][nt] = __builtin_amdgcn_mfma_f32_16x16x32_bf16(
              afl[ct], bfh[nt], acc[ct][nt], 0, 0, 0);
      const short8x* Xl = (const short8x*)Xs + 4096 + dc * 512 + l;
      #pragma unroll
      for (int nt = 0; nt < 8; ++nt) bfl[nt] = Xl[nt * 64];
      #pragma unroll
      for (int nt = 0; nt < 8; ++nt)
        #pragma unroll
        for (int ct = 0; ct < 4; ++ct)
          acc[ct][nt] = __builtin_amdgcn_mfma_f32_16x16x32_bf16(
              afh[ct], bfl[nt], acc[ct][nt], 0, 0, 0);
    }

    const int cbase = khp * 512 + wv * 64;
    float4 wq[4];
    #pragma unroll
    for (int ct = 0; ct < 4; ++ct)
      wq[ct] = *(const float4*)(wsq + cbase + ct * 16 + g * 4);

    #pragma unroll
    for (int nt = 0; nt < 8; ++nt) {
      u64 best = ~0ull;
      #pragma unroll
      for (int ct = 0; ct < 4; ++ct) {
        const float* wqv = (const float*)&wq[ct];
        #pragma unroll
        for (int r = 0; r < 4; ++r) {
          float dist = wqv[r] - 2.0f * acc[ct][nt][r];
          unsigned u = __float_as_uint(dist);
          u = (u & 0x80000000u) ? ~u : (u | 0x80000000u);
          u64 key = ((u64)u << 32) | (unsigned)(cbase + ct * 16 + g * 4 + r);
          best = best < key ? best : key;
        }
      }
      u64 o = __shfl_xor(best, 16, 64); best = o < best ? o : best;
      o = __shfl_xor(best, 32, 64);     best = o < best ? o : best;
      if (l < 16) {
        const int j = nt * 16 + l;
        if (khp == 0) Red[wv][j] = best;
        else { u64 p = Red[wv][j]; Red[wv][j] = best < p ? best : p; }
      }
    }
  }

  __syncthreads();
  if (tid < 128) {
    u64 best = Red[0][tid];
    #pragma unroll
    for (int ww = 1; ww < 8; ++ww) {
      u64 o = Red[ww][tid];
      best = o < best ? o : best;
    }
    idx[n0 + tid] = (int)(best & 0xffffffffull);
  }
}

#define WPITCH 1028
__global__ __launch_bounds__(256) void gather2_kernel(
    const float* __restrict__ wt, const int* __restrict__ idx,
    float* __restrict__ out) {
  __shared__ __align__(16) float Ws[16 * WPITCH];
  const int tid = threadIdx.x;
  const int bimg = blockIdx.x >> 4;
  const int c0 = (blockIdx.x & 15) * 16;
  int4 kv = *(const int4*)(idx + bimg * 1024 + tid * 4);
  #pragma unroll
  for (int cc = 0; cc < 16; ++cc) {
    float4 v = *(const float4*)(wt + (size_t)(c0 + cc) * KCODE + tid * 4);
    *(float4*)(Ws + cc * WPITCH + tid * 4) = v;
  }
  __syncthreads();
  float* ob = out + (size_t)bimg * DDIM * 1024 + (size_t)c0 * 1024 + tid * 4;
  #pragma unroll
  for (int cc = 0; cc < 16; ++cc) {
    const float* wr = Ws + cc * WPITCH;
    float4 v;
    v.x = wr[kv.x]; v.y = wr[kv.y]; v.z = wr[kv.z]; v.w = wr[kv.w];
    *(float4*)(ob + (size_t)cc * 1024) = v;
    *(float4*)(ob + (size_t)cc * 1024 + 8388608) = v;
  }
}

__global__ void gather_kernel(const float* __restrict__ w, const int* __restrict__ idx,
                              float* __restrict__ out) {
  const int gi = blockIdx.x * 256 + threadIdx.x;
  const int hw4 = gi & 255;
  const int c = (gi >> 8) & 255;
  const int b = gi >> 16;
  int4 kv = *(const int4*)(idx + b * 1024 + hw4 * 4);
  float4 v;
  v.x = w[(size_t)kv.x * 256 + c];
  v.y = w[(size_t)kv.y * 256 + c];
  v.z = w[(size_t)kv.z * 256 + c];
  v.w = w[(size_t)kv.w * 256 + c];
  float4* o = (float4*)out;
  o[gi] = v;
  o[gi + 2097152] = v;
}

extern "C" void kernel_launch(void* const* d_in, const int* in_sizes, int n_in,
                              void* d_out, int out_size, void* d_ws, size_t ws_size,
                              hipStream_t stream) {
  const float* z = (const float*)d_in[0];   // [32,256,32,32] fp32
  const float* w = (const float*)d_in[1];   // [1024,256] fp32
  float* out = (float*)d_out;

  float* wsq = (float*)d_ws;                 // 4 KB @ 0
  const size_t need_fused = 4096 + 1572864;  // wsq + Wp (1.5 MB)

  if (ws_size >= need_fused) {
    u16* Wp = (u16*)((char*)d_ws + 4096);
    pack_w<<<128, 256, 0, stream>>>(w, Wp, wsq);
    argmin_fused<<<512, 1024, 0, stream>>>(z, w, Wp, wsq, out);
    return;
  }

  // -------- fallback: R2-style pipeline (Wp scratch inside codes_bar) -------
  int* idx = (int*)((char*)d_ws + 4096);
  const size_t need = 4096 + 131072 + 1048576;
  const bool ws_ok = ws_size >= need;
  float* wt = ws_ok ? (float*)((char*)d_ws + 4096 + 131072)
                    : out + (size_t)out_size - 262144;
  u16* Wp = (u16*)(out + 8388608);

  pack_w<<<128, 256, 0, stream>>>(w, Wp, wsq);
  wt_kernel<<<dim3(16, 4), 256, 0, stream>>>(w, wt);
  argmin_mfma_v2<<<256, 512, 0, stream>>>(z, Wp, wsq, idx);
  if (ws_ok)
    gather2_kernel<<<512, 256, 0, stream>>>(wt, idx, out);
  else
    gather_kernel<<<2097152 / 256, 256, 0, stream>>>(w, idx, out);
}